// Round 2
// baseline (547.855 us; speedup 1.0000x reference)
//
#include <hip/hip_runtime.h>
#include <stdint.h>

#define BATCH 2048
#define NUM_CLASSES 50257
#define KLBL 20

__device__ __forceinline__ float log_sigmoid(float z) {
    // log(sigmoid(z)) = min(z,0) - log1p(exp(-|z|)), numerically stable.
    float e = __expf(-fabsf(z));
    return fminf(z, 0.0f) - __logf(1.0f + e);
}

__global__ __launch_bounds__(256) void mlsm_row_kernel(
    const float* __restrict__ x,
    const int* __restrict__ tgt,
    float* __restrict__ row_loss) {

    const int row = blockIdx.x;
    const float* __restrict__ xr = x + (size_t)row * NUM_CLASSES;
    const int tid = threadIdx.x;

    __shared__ int s_tgt[KLBL];
    if (tid < KLBL) s_tgt[tid] = tgt[row * KLBL + tid];

    // ---- streaming sum of logsig(-x) over the whole row (float4 body) ----
    // Row base is 4B-aligned but not necessarily 16B-aligned (C odd).
    uintptr_t addr = (uintptr_t)xr;
    const int lead = (int)(((16u - (unsigned)(addr & 15u)) & 15u) >> 2); // 0..3 elems
    const int nbody4 = (NUM_CLASSES - lead) >> 2;
    const int tail_start = lead + (nbody4 << 2);

    float acc = 0.0f;
    if (tid < lead) acc += log_sigmoid(-xr[tid]);

    const float4* __restrict__ xb = (const float4*)(xr + lead);

    // 2x float4 per iteration: two independent 16B loads in flight per wave
    // iteration before the dependent exp/log chain.
    int i = tid;
    const int nbody4_2 = nbody4 - 256;  // last index where i+256 is valid
    for (; i < nbody4_2; i += 512) {
        float4 v0 = xb[i];
        float4 v1 = xb[i + 256];
        acc += log_sigmoid(-v0.x);
        acc += log_sigmoid(-v0.y);
        acc += log_sigmoid(-v0.z);
        acc += log_sigmoid(-v0.w);
        acc += log_sigmoid(-v1.x);
        acc += log_sigmoid(-v1.y);
        acc += log_sigmoid(-v1.z);
        acc += log_sigmoid(-v1.w);
    }
    for (; i < nbody4; i += 256) {
        float4 v = xb[i];
        acc += log_sigmoid(-v.x);
        acc += log_sigmoid(-v.y);
        acc += log_sigmoid(-v.z);
        acc += log_sigmoid(-v.w);
    }
    for (int j = tail_start + tid; j < NUM_CLASSES; j += 256) {
        acc += log_sigmoid(-xr[j]);
    }

    // ---- block reduction of acc ----
    #pragma unroll
    for (int off = 32; off > 0; off >>= 1) acc += __shfl_down(acc, off, 64);

    __shared__ float s_red[4];
    const int wave = tid >> 6;
    if ((tid & 63) == 0) s_red[wave] = acc;
    __syncthreads();

    // ---- wave 0: label corrections + final row loss ----
    if (tid < 64) {
        const int lane = tid;
        float pos = 0.0f;   // logsig(x[t_k]) per occurrence
        float adj = 0.0f;   // logsig(-x[t_k]) for unique labels only
        float cnt = 0.0f;   // 1 per unique label
        if (lane < KLBL) {
            const int t = s_tgt[lane];
            const float v = xr[t];
            pos = log_sigmoid(v);
            bool unique = true;
            #pragma unroll
            for (int j = 0; j < KLBL; ++j) {
                if (j < lane && s_tgt[j] == t) unique = false;
            }
            if (unique) { adj = log_sigmoid(-v); cnt = 1.0f; }
        }
        #pragma unroll
        for (int off = 32; off > 0; off >>= 1) {
            pos += __shfl_down(pos, off, 64);
            adj += __shfl_down(adj, off, 64);
            cnt += __shfl_down(cnt, off, 64);
        }
        if (lane == 0) {
            const float neg_full = s_red[0] + s_red[1] + s_red[2] + s_red[3];
            const float neg_sum  = neg_full - adj;
            const float neg_cnt  = (float)NUM_CLASSES - cnt;
            const float pos_mean = pos * (1.0f / (float)KLBL);
            row_loss[row] = pos_mean + neg_sum / neg_cnt;
        }
    }
}

__global__ __launch_bounds__(256) void mlsm_final_reduce(
    const float* __restrict__ row_loss,
    float* __restrict__ out) {

    float acc = 0.0f;
    for (int i = threadIdx.x; i < BATCH; i += 256) acc += row_loss[i];

    #pragma unroll
    for (int off = 32; off > 0; off >>= 1) acc += __shfl_down(acc, off, 64);

    __shared__ float s_red[4];
    const int wave = threadIdx.x >> 6;
    if ((threadIdx.x & 63) == 0) s_red[wave] = acc;
    __syncthreads();

    if (threadIdx.x == 0) {
        const float total = s_red[0] + s_red[1] + s_red[2] + s_red[3];
        out[0] = -total / (float)BATCH;
    }
}

extern "C" void kernel_launch(void* const* d_in, const int* in_sizes, int n_in,
                              void* d_out, int out_size, void* d_ws, size_t ws_size,
                              hipStream_t stream) {
    const float* inputs = (const float*)d_in[0];
    const int* targets  = (const int*)d_in[1];
    float* out = (float*)d_out;
    float* row_loss = (float*)d_ws;  // 2048 floats

    mlsm_row_kernel<<<BATCH, 256, 0, stream>>>(inputs, targets, row_loss);
    mlsm_final_reduce<<<1, 256, 0, stream>>>(row_loss, out);
}

// Round 5
// 515.377 us; speedup vs baseline: 1.0630x; 1.0630x over previous
//
#include <hip/hip_runtime.h>
#include <stdint.h>

#define BATCH 2048
#define NUM_CLASSES 50257
#define KLBL 20

typedef float fvec4 __attribute__((ext_vector_type(4)));

__device__ __forceinline__ float log_sigmoid(float z) {
    // log(sigmoid(z)) = min(z,0) - log1p(exp(-|z|)), numerically stable.
    float e = __expf(-fabsf(z));
    return fminf(z, 0.0f) - __logf(1.0f + e);
}

__global__ __launch_bounds__(256) void mlsm_row_kernel(
    const float* __restrict__ x,
    const int* __restrict__ tgt,
    float* __restrict__ row_loss) {

    const int row = blockIdx.x;
    const float* __restrict__ xr = x + (size_t)row * NUM_CLASSES;
    const int tid = threadIdx.x;

    __shared__ int s_tgt[KLBL];
    if (tid < KLBL) s_tgt[tid] = tgt[row * KLBL + tid];

    // ---- streaming sum of logsig(-x) over the whole row ----
    // Row base is 4B-aligned but not necessarily 16B-aligned (C odd).
    uintptr_t addr = (uintptr_t)xr;
    const int lead = (int)(((16u - (unsigned)(addr & 15u)) & 15u) >> 2); // 0..3 elems
    const int nbody4 = (NUM_CLASSES - lead) >> 2;
    const int tail_start = lead + (nbody4 << 2);

    float acc = 0.0f;
    if (tid < lead) acc += log_sigmoid(-xr[tid]);

    const fvec4* __restrict__ xb = (const fvec4*)(xr + lead);

    // 4x fvec4 per iteration: four independent 16B nontemporal loads in
    // flight per wave before the dependent exp/log chain (read-once stream,
    // skip cache allocation).
    int i = tid;
    const int lim4 = nbody4 - 768;  // last i where i+768 is valid
    for (; i < lim4; i += 1024) {
        fvec4 v0 = __builtin_nontemporal_load(&xb[i]);
        fvec4 v1 = __builtin_nontemporal_load(&xb[i + 256]);
        fvec4 v2 = __builtin_nontemporal_load(&xb[i + 512]);
        fvec4 v3 = __builtin_nontemporal_load(&xb[i + 768]);
        acc += log_sigmoid(-v0.x); acc += log_sigmoid(-v0.y);
        acc += log_sigmoid(-v0.z); acc += log_sigmoid(-v0.w);
        acc += log_sigmoid(-v1.x); acc += log_sigmoid(-v1.y);
        acc += log_sigmoid(-v1.z); acc += log_sigmoid(-v1.w);
        acc += log_sigmoid(-v2.x); acc += log_sigmoid(-v2.y);
        acc += log_sigmoid(-v2.z); acc += log_sigmoid(-v2.w);
        acc += log_sigmoid(-v3.x); acc += log_sigmoid(-v3.y);
        acc += log_sigmoid(-v3.z); acc += log_sigmoid(-v3.w);
    }
    for (; i < nbody4; i += 256) {
        fvec4 v = __builtin_nontemporal_load(&xb[i]);
        acc += log_sigmoid(-v.x); acc += log_sigmoid(-v.y);
        acc += log_sigmoid(-v.z); acc += log_sigmoid(-v.w);
    }
    for (int j = tail_start + tid; j < NUM_CLASSES; j += 256) {
        acc += log_sigmoid(-xr[j]);
    }

    // ---- block reduction of acc ----
    #pragma unroll
    for (int off = 32; off > 0; off >>= 1) acc += __shfl_down(acc, off, 64);

    __shared__ float s_red[4];
    const int wave = tid >> 6;
    if ((tid & 63) == 0) s_red[wave] = acc;
    __syncthreads();

    // ---- wave 0: label corrections + final row loss ----
    if (tid < 64) {
        const int lane = tid;
        float pos = 0.0f;   // logsig(x[t_k]) per occurrence
        float adj = 0.0f;   // logsig(-x[t_k]) for unique labels only
        float cnt = 0.0f;   // 1 per unique label
        if (lane < KLBL) {
            const int t = s_tgt[lane];
            const float v = xr[t];
            pos = log_sigmoid(v);
            bool unique = true;
            #pragma unroll
            for (int j = 0; j < KLBL; ++j) {
                if (j < lane && s_tgt[j] == t) unique = false;
            }
            if (unique) { adj = log_sigmoid(-v); cnt = 1.0f; }
        }
        #pragma unroll
        for (int off = 32; off > 0; off >>= 1) {
            pos += __shfl_down(pos, off, 64);
            adj += __shfl_down(adj, off, 64);
            cnt += __shfl_down(cnt, off, 64);
        }
        if (lane == 0) {
            const float neg_full = s_red[0] + s_red[1] + s_red[2] + s_red[3];
            const float neg_sum  = neg_full - adj;
            const float neg_cnt  = (float)NUM_CLASSES - cnt;
            const float pos_mean = pos * (1.0f / (float)KLBL);
            row_loss[row] = pos_mean + neg_sum / neg_cnt;
        }
    }
}

__global__ __launch_bounds__(256) void mlsm_final_reduce(
    const float* __restrict__ row_loss,
    float* __restrict__ out) {

    float acc = 0.0f;
    for (int i = threadIdx.x; i < BATCH; i += 256) acc += row_loss[i];

    #pragma unroll
    for (int off = 32; off > 0; off >>= 1) acc += __shfl_down(acc, off, 64);

    __shared__ float s_red[4];
    const int wave = threadIdx.x >> 6;
    if ((threadIdx.x & 63) == 0) s_red[wave] = acc;
    __syncthreads();

    if (threadIdx.x == 0) {
        const float total = s_red[0] + s_red[1] + s_red[2] + s_red[3];
        out[0] = -total / (float)BATCH;
    }
}

extern "C" void kernel_launch(void* const* d_in, const int* in_sizes, int n_in,
                              void* d_out, int out_size, void* d_ws, size_t ws_size,
                              hipStream_t stream) {
    const float* inputs = (const float*)d_in[0];
    const int* targets  = (const int*)d_in[1];
    float* out = (float*)d_out;
    float* row_loss = (float*)d_ws;  // 2048 floats

    mlsm_row_kernel<<<BATCH, 256, 0, stream>>>(inputs, targets, row_loss);
    mlsm_final_reduce<<<1, 256, 0, stream>>>(row_loss, out);
}